// Round 6
// baseline (154.298 us; speedup 1.0000x reference)
//
#include <hip/hip_runtime.h>
#include <hip/hip_bf16.h>

// h:[N,128] f32, src/dst:[E] i32, W1:[128,256] f32, b1:[128] f32, W2:[1,128] f32,
// b2,W3,b3: scalars f32  -> out:[E] f32
// Factorization: W1@concat(h[s],h[d]) = W1[:,:128]@h[s] + W1[:,128:]@h[d]
// Stage 0 (prep): W1 f32 -> fragment-ordered bf16 table (64 KB) + bias256 f32.
// Stage 1 (node, MFMA bf16): AB[n][0:128] = W1[:,:128]@h[n]+b1 ; AB[n][128:256]
//   = W1[:,128:]@h[n].  v3: 64 nodes/block, ONE barrier, 64 MFMA/wave
//   (R5 post-mortem: 4 shallow tiles exposed ~900cyc load latency per barrier).
// Stage 2 (edge): out = sigmoid(relu(W3*relu(W2 . relu(A[s]+B[d]) + b2) + b3))
//   v3: 8 lanes/edge, 4 independent uint4 loads/lane (deeper MLP), 8 edges/wave.

#define HID 128

using short8 = __attribute__((ext_vector_type(8))) short;  // 8 bf16 = 4 VGPRs
using f32x4  = __attribute__((ext_vector_type(4))) float;

typedef unsigned int uint32;

static __device__ __forceinline__ unsigned short f2bf(float f) {  // RNE f32->bf16
    uint32 u = __float_as_uint(f);
    u += 0x7fffu + ((u >> 16) & 1u);
    return (unsigned short)(u >> 16);
}
static __device__ __forceinline__ uint32 pk2(float a, float b) {
    return ((uint32)f2bf(a)) | (((uint32)f2bf(b)) << 16);
}
static __device__ __forceinline__ float bflo(uint32 u) { return __uint_as_float(u << 16); }
static __device__ __forceinline__ float bfhi(uint32 u) { return __uint_as_float(u & 0xffff0000u); }

// ---------------------------------------------------------------------------
// Stage 0: weight prep. wtab[(widx*64+lane)*8+j] = bf16(W1[row][col+j]);
// widx=(wave*4+ot)*4+ks; o=wave*64+ot*16+(lane&15); row=o&127;
// col=(o>=128?128:0)+ks*32+(lane>>4)*8.  bias256[o] = o<128 ? b1[o] : 0.
// ---------------------------------------------------------------------------
__global__ __launch_bounds__(256) void prep_kernel(
    const float* __restrict__ W1,
    const float* __restrict__ b1,
    unsigned short* __restrict__ wtab,
    float* __restrict__ bias256)
{
    const int idx  = blockIdx.x * 256 + threadIdx.x;  // 0..4095
    const int widx = idx >> 6;
    const int lane = idx & 63;
    const int wave = widx >> 4;
    const int ot   = (widx >> 2) & 3;
    const int ks   = widx & 3;
    const int o    = wave * 64 + ot * 16 + (lane & 15);
    const int row  = o & 127;
    const int col  = ((o >= 128) ? 128 : 0) + ks * 32 + (lane >> 4) * 8;
    const float* p = W1 + row * 256 + col;
    float4 f0 = *(const float4*)p;
    float4 f1 = *(const float4*)(p + 4);
    uint4 st;
    st.x = pk2(f0.x, f0.y);
    st.y = pk2(f0.z, f0.w);
    st.z = pk2(f1.x, f1.y);
    st.w = pk2(f1.z, f1.w);
    *(uint4*)(wtab + (size_t)idx * 8) = st;

    if (idx < 256) bias256[idx] = (idx < 128) ? b1[idx] : 0.0f;
}

// ---------------------------------------------------------------------------
// Stage 1 (v3): 64 nodes x 256 outputs per block, single barrier.
// mfma_f32_16x16x32_bf16 (m89): A[m=lane&15][k=quad*8+j], B[k=quad*8+j][n=lane&15],
// C/D col=lane&15 (node-within-tile), row=quad*4+reg (output).
// LDS tile: 64 rows x 128 ushort (16 KB). 8B unit u (0..31) of row r stored at
// ushort offset r*128 + ((u ^ ((r&15)<<1))<<2).  Swizzle keeps both staging
// ds_write_b64 and frag ds_read_b128 at <=2-way bank aliasing (free, m136);
// even-XOR preserves unit-pair adjacency so b128 frag reads stay legal.
// ---------------------------------------------------------------------------
__global__ __launch_bounds__(256) void node_stage_v3_kernel(
    const float* __restrict__ h,             // [N,128]
    const unsigned short* __restrict__ wtab, // [64*64*8]
    const float* __restrict__ bias256,       // [256]
    unsigned short* __restrict__ AB,         // [N,256] out
    int N)
{
    __shared__ unsigned short hs[64 * 128];  // 16 KB

    const int t    = threadIdx.x;
    const int lane = t & 63;
    const int wave = t >> 6;
    const int c    = lane & 15;
    const int q    = lane >> 4;

    // Weight frags: coalesced, no conversion (L2-hot wtab).
    short8 vfrag[4][4];
    float4 bias[4];
#pragma unroll
    for (int ot = 0; ot < 4; ++ot) {
#pragma unroll
        for (int ks = 0; ks < 4; ++ks) {
            int widx = (wave * 4 + ot) * 4 + ks;
            vfrag[ot][ks] = *(const short8*)(wtab + ((size_t)widx * 64 + lane) * 8);
        }
        bias[ot] = *(const float4*)(bias256 + wave * 64 + ot * 16 + q * 4);
    }

    const int n0 = blockIdx.x * 64;

    // --- staging: 8 independent coalesced float4 loads per thread ---
    // element-quad index within tile: e4 = j*256 + t  (j=0..7); row rl=e4>>5,
    // unit u=e4&31.  Issue all loads first (deep MLP), then cvt+ds_write.
    float4 g[8];
#pragma unroll
    for (int j = 0; j < 8; ++j) {
        int e4 = j * 256 + t;
        int rl = e4 >> 5;
        int grow = n0 + rl;
        if (grow >= N) grow = N - 1;              // tail clamp (dup read, unstored)
        g[j] = *(const float4*)(h + (size_t)grow * HID + (e4 & 31) * 4);
    }
#pragma unroll
    for (int j = 0; j < 8; ++j) {
        int e4 = j * 256 + t;
        int rl = e4 >> 5;
        int u  = e4 & 31;
        uint2 w2;
        w2.x = pk2(g[j].x, g[j].y);
        w2.y = pk2(g[j].z, g[j].w);
        *(uint2*)(hs + rl * 128 + ((u ^ ((rl & 15) << 1)) << 2)) = w2;
    }
    __syncthreads();  // the ONLY barrier

    f32x4 acc[4][4];  // [nt][ot]
#pragma unroll
    for (int nt = 0; nt < 4; ++nt)
#pragma unroll
        for (int ot = 0; ot < 4; ++ot) acc[nt][ot] = (f32x4){0.f, 0.f, 0.f, 0.f};

#pragma unroll
    for (int ks = 0; ks < 4; ++ks) {
        short8 hfrag[4];
#pragma unroll
        for (int nt = 0; nt < 4; ++nt) {
            int r  = nt * 16 + c;
            int u0 = ks * 8 + q * 2;                     // even
            hfrag[nt] = *(const short8*)(hs + r * 128 + ((u0 ^ (c << 1)) << 2));
        }
#pragma unroll
        for (int nt = 0; nt < 4; ++nt)
#pragma unroll
            for (int ot = 0; ot < 4; ++ot)
                acc[nt][ot] = __builtin_amdgcn_mfma_f32_16x16x32_bf16(
                    vfrag[ot][ks], hfrag[nt], acc[nt][ot], 0, 0, 0);
    }

#pragma unroll
    for (int nt = 0; nt < 4; ++nt) {
        const int node = n0 + nt * 16 + c;
        if (node < N) {
#pragma unroll
            for (int ot = 0; ot < 4; ++ot) {
                int o_base = wave * 64 + ot * 16 + q * 4;
                uint2 st;
                st.x = pk2(acc[nt][ot][0] + bias[ot].x, acc[nt][ot][1] + bias[ot].y);
                st.y = pk2(acc[nt][ot][2] + bias[ot].z, acc[nt][ot][3] + bias[ot].w);
                *(uint2*)(AB + (size_t)node * 256 + o_base) = st;
            }
        }
    }
}

// ---------------------------------------------------------------------------
// Stage 1 (v1 fallback, ws only fits AB): in-kernel weight conversion.
// ---------------------------------------------------------------------------
__global__ __launch_bounds__(256) void node_stage_kernel(
    const float* __restrict__ h,
    const float* __restrict__ W1,
    const float* __restrict__ b1,
    unsigned short* __restrict__ AB,
    int N)
{
    __shared__ unsigned short hsb[16 * 256];

    const int t    = threadIdx.x;
    const int lane = t & 63;
    const int wave = t >> 6;
    const int c    = lane & 15;
    const int q    = lane >> 4;

    short8 vfrag[4][4];
    float  bias[4][4];
#pragma unroll
    for (int ot = 0; ot < 4; ++ot) {
#pragma unroll
        for (int ks = 0; ks < 4; ++ks) {
            int o   = wave * 64 + ot * 16 + c;
            int row = o & 127;
            int col = ((o >= 128) ? 128 : 0) + ks * 32 + q * 8;
            const float* p = W1 + row * 256 + col;
            float4 f0 = *(const float4*)p;
            float4 f1 = *(const float4*)(p + 4);
            short8 v;
            v[0] = (short)f2bf(f0.x); v[1] = (short)f2bf(f0.y);
            v[2] = (short)f2bf(f0.z); v[3] = (short)f2bf(f0.w);
            v[4] = (short)f2bf(f1.x); v[5] = (short)f2bf(f1.y);
            v[6] = (short)f2bf(f1.z); v[7] = (short)f2bf(f1.w);
            vfrag[ot][ks] = v;
        }
#pragma unroll
        for (int r = 0; r < 4; ++r) {
            int o = wave * 64 + ot * 16 + q * 4 + r;
            bias[ot][r] = (o < 128) ? b1[o] : 0.0f;
        }
    }

    const int sr = t >> 4;
    const int sj = t & 15;
    const int ntiles = N >> 4;
    for (int tile = blockIdx.x; tile < ntiles; tile += gridDim.x) {
        int n0 = tile * 16;
        {
            const float* p = h + (size_t)(n0 + sr) * HID + sj * 8;
            float4 f0 = *(const float4*)p;
            float4 f1 = *(const float4*)(p + 4);
            uint4 st;
            st.x = pk2(f0.x, f0.y);
            st.y = pk2(f0.z, f0.w);
            st.z = pk2(f1.x, f1.y);
            st.w = pk2(f1.z, f1.w);
            *(uint4*)(hsb + sr * 256 + ((sj ^ sr) * 8)) = st;
        }
        __syncthreads();

        short8 hfrag[4];
#pragma unroll
        for (int ks = 0; ks < 4; ++ks) {
            int blk = (ks * 4 + q) ^ c;
            hfrag[ks] = *(const short8*)(hsb + c * 256 + blk * 8);
        }

        f32x4 acc[4];
#pragma unroll
        for (int ot = 0; ot < 4; ++ot) acc[ot] = (f32x4){0.f, 0.f, 0.f, 0.f};
#pragma unroll
        for (int ks = 0; ks < 4; ++ks)
#pragma unroll
            for (int ot = 0; ot < 4; ++ot)
                acc[ot] = __builtin_amdgcn_mfma_f32_16x16x32_bf16(
                    vfrag[ot][ks], hfrag[ks], acc[ot], 0, 0, 0);

        const int node = n0 + c;
#pragma unroll
        for (int ot = 0; ot < 4; ++ot) {
            int o_base = wave * 64 + ot * 16 + q * 4;
            uint2 st;
            st.x = pk2(acc[ot][0] + bias[ot][0], acc[ot][1] + bias[ot][1]);
            st.y = pk2(acc[ot][2] + bias[ot][2], acc[ot][3] + bias[ot][3]);
            *(uint2*)(AB + (size_t)node * 256 + o_base) = st;
        }
        __syncthreads();
    }
}

// ---------------------------------------------------------------------------
// Stage 2 (v3): 8 edges/wave, 8 lanes/edge, 16 ch/lane => 4 independent uint4
// loads per lane (deep memory-level parallelism on the random gather).
// ---------------------------------------------------------------------------
__global__ __launch_bounds__(256) void edge_stage_kernel(
    const unsigned short* __restrict__ AB,  // [N,256] bf16 bits
    const int* __restrict__ src,
    const int* __restrict__ dst,
    const float* __restrict__ W2,   // [128]
    const float* __restrict__ b2,
    const float* __restrict__ W3,
    const float* __restrict__ b3,
    float* __restrict__ out,        // [E]
    int E)
{
    const int lane = threadIdx.x & 63;
    const int wave = threadIdx.x >> 6;
    const int sub  = lane & 7;      // lane within edge group (8)
    const int eg   = lane >> 3;     // edge slot 0..7 in this wave
    const int e    = blockIdx.x * 32 + wave * 8 + eg;
    if (e >= E) return;

    const int s = src[e];
    const int d = dst[e];

    const unsigned short* pa = AB + (size_t)s * 256 + sub * 16;
    const unsigned short* pb = AB + (size_t)d * 256 + 128 + sub * 16;
    const uint4 ua0 = *(const uint4*)pa;
    const uint4 ua1 = *(const uint4*)(pa + 8);
    const uint4 ub0 = *(const uint4*)pb;
    const uint4 ub1 = *(const uint4*)(pb + 8);

    const float4 w0 = *(const float4*)(W2 + sub * 16);
    const float4 w1 = *(const float4*)(W2 + sub * 16 + 4);
    const float4 w2v = *(const float4*)(W2 + sub * 16 + 8);
    const float4 w3v = *(const float4*)(W2 + sub * 16 + 12);

    float p;
    {
        float t0 = fmaxf(bflo(ua0.x) + bflo(ub0.x), 0.0f);
        float t1 = fmaxf(bfhi(ua0.x) + bfhi(ub0.x), 0.0f);
        float t2 = fmaxf(bflo(ua0.y) + bflo(ub0.y), 0.0f);
        float t3 = fmaxf(bfhi(ua0.y) + bfhi(ub0.y), 0.0f);
        float t4 = fmaxf(bflo(ua0.z) + bflo(ub0.z), 0.0f);
        float t5 = fmaxf(bfhi(ua0.z) + bfhi(ub0.z), 0.0f);
        float t6 = fmaxf(bflo(ua0.w) + bflo(ub0.w), 0.0f);
        float t7 = fmaxf(bfhi(ua0.w) + bfhi(ub0.w), 0.0f);
        p = t0 * w0.x;
        p = fmaf(t1, w0.y, p);
        p = fmaf(t2, w0.z, p);
        p = fmaf(t3, w0.w, p);
        p = fmaf(t4, w1.x, p);
        p = fmaf(t5, w1.y, p);
        p = fmaf(t6, w1.z, p);
        p = fmaf(t7, w1.w, p);
        float s0 = fmaxf(bflo(ua1.x) + bflo(ub1.x), 0.0f);
        float s1 = fmaxf(bfhi(ua1.x) + bfhi(ub1.x), 0.0f);
        float s2 = fmaxf(bflo(ua1.y) + bflo(ub1.y), 0.0f);
        float s3 = fmaxf(bfhi(ua1.y) + bfhi(ub1.y), 0.0f);
        float s4 = fmaxf(bflo(ua1.z) + bflo(ub1.z), 0.0f);
        float s5 = fmaxf(bfhi(ua1.z) + bfhi(ub1.z), 0.0f);
        float s6 = fmaxf(bflo(ua1.w) + bflo(ub1.w), 0.0f);
        float s7 = fmaxf(bfhi(ua1.w) + bfhi(ub1.w), 0.0f);
        p = fmaf(s0, w2v.x, p);
        p = fmaf(s1, w2v.y, p);
        p = fmaf(s2, w2v.z, p);
        p = fmaf(s3, w2v.w, p);
        p = fmaf(s4, w3v.x, p);
        p = fmaf(s5, w3v.y, p);
        p = fmaf(s6, w3v.z, p);
        p = fmaf(s7, w3v.w, p);
    }

#pragma unroll
    for (int m = 4; m >= 1; m >>= 1) p += __shfl_xor(p, m, 64);

    if (sub == 0) {
        float y2 = fmaxf(p + b2[0], 0.0f);
        float y3 = fmaxf(W3[0] * y2 + b3[0], 0.0f);
        out[e] = 1.0f / (1.0f + __expf(-y3));
    }
}

// ---------------------------------------------------------------------------
// Fallback (ws too small for AB): direct per-edge MLP, fp32. Correct, slow.
// ---------------------------------------------------------------------------
__global__ __launch_bounds__(256) void edge_direct_kernel(
    const float* __restrict__ h,
    const int* __restrict__ src,
    const int* __restrict__ dst,
    const float* __restrict__ W1,
    const float* __restrict__ b1,
    const float* __restrict__ W2,
    const float* __restrict__ b2,
    const float* __restrict__ W3,
    const float* __restrict__ b3,
    float* __restrict__ out,
    int E)
{
    __shared__ float x[256];
    __shared__ float red[4];
    const int e = blockIdx.x;
    if (e >= E) return;
    const int t = threadIdx.x;
    const int s = src[e];
    const int d = dst[e];

    if (t < 128) x[t] = h[(size_t)s * HID + t];
    else         x[t] = h[(size_t)d * HID + (t - 128)];
    __syncthreads();

    float contrib = 0.0f;
    if (t < 128) {
        float acc = b1[t];
        const float* wr = W1 + t * 256;
        for (int k = 0; k < 256; ++k) acc = fmaf(wr[k], x[k], acc);
        contrib = fmaxf(acc, 0.0f) * W2[t];
    }
#pragma unroll
    for (int m = 32; m >= 1; m >>= 1) contrib += __shfl_xor(contrib, m, 64);
    if ((t & 63) == 0) red[t >> 6] = contrib;
    __syncthreads();
    if (t == 0) {
        float p = red[0] + red[1] + red[2] + red[3];
        float y2 = fmaxf(p + b2[0], 0.0f);
        float y3 = fmaxf(W3[0] * y2 + b3[0], 0.0f);
        out[e] = 1.0f / (1.0f + __expf(-y3));
    }
}

extern "C" void kernel_launch(void* const* d_in, const int* in_sizes, int n_in,
                              void* d_out, int out_size, void* d_ws, size_t ws_size,
                              hipStream_t stream) {
    const float* h   = (const float*)d_in[0];
    const int*   src = (const int*)d_in[1];
    const int*   dst = (const int*)d_in[2];
    const float* W1  = (const float*)d_in[3];
    const float* b1  = (const float*)d_in[4];
    const float* W2  = (const float*)d_in[5];
    const float* b2  = (const float*)d_in[6];
    const float* W3  = (const float*)d_in[7];
    const float* b3  = (const float*)d_in[8];
    float* out = (float*)d_out;

    const int N = in_sizes[0] / HID;   // 100000
    const int E = in_sizes[1];         // 500000

    const size_t ab_bytes   = (size_t)N * 256 * sizeof(unsigned short);
    const size_t wtab_off   = (ab_bytes + 255) & ~(size_t)255;
    const size_t wtab_bytes = (size_t)64 * 64 * 8 * sizeof(unsigned short);  // 64 KB
    const size_t bias_off   = wtab_off + wtab_bytes;
    const size_t need_v2    = bias_off + 256 * sizeof(float);

    if (need_v2 <= ws_size) {
        unsigned short* AB   = (unsigned short*)d_ws;
        unsigned short* wtab = (unsigned short*)((char*)d_ws + wtab_off);
        float* bias256       = (float*)((char*)d_ws + bias_off);
        prep_kernel<<<16, 256, 0, stream>>>(W1, b1, wtab, bias256);
        const int nblocks = (N + 63) / 64;
        node_stage_v3_kernel<<<nblocks, 256, 0, stream>>>(h, wtab, bias256, AB, N);
        edge_stage_kernel<<<(E + 31) / 32, 256, 0, stream>>>(AB, src, dst, W2, b2, W3, b3, out, E);
    } else if (ab_bytes <= ws_size) {
        unsigned short* AB = (unsigned short*)d_ws;
        node_stage_kernel<<<1563, 256, 0, stream>>>(h, W1, b1, AB, N);
        edge_stage_kernel<<<(E + 31) / 32, 256, 0, stream>>>(AB, src, dst, W2, b2, W3, b3, out, E);
    } else {
        edge_direct_kernel<<<E, 256, 0, stream>>>(h, src, dst, W1, b1, W2, b2, W3, b3, out, E);
    }
}

// Round 7
// 152.867 us; speedup vs baseline: 1.0094x; 1.0094x over previous
//
#include <hip/hip_runtime.h>
#include <hip/hip_bf16.h>

// h:[N,128] f32, src/dst:[E] i32, W1:[128,256] f32, b1:[128] f32, W2:[1,128] f32,
// b2,W3,b3: scalars f32  -> out:[E] f32
// Factorization: W1@concat(h[s],h[d]) = W1[:,:128]@h[s] + W1[:,128:]@h[d]
// Stage 0 (prep): W1 f32 -> fragment-ordered bf16 table (64 KB) + bias256 f32.
// Stage 1 (node, MFMA bf16, v3): 64 nodes/block, one barrier, 64 MFMA/wave.
// Stage 2 (edge, v4): 16 edges/wave = 2 per 8-lane group; 8 outstanding 16B
//   gathers per lane issued before any unpack (deep MLP to hide the random
//   gather latency); W2 registers shared across both edges.

#define HID 128

using short8 = __attribute__((ext_vector_type(8))) short;  // 8 bf16 = 4 VGPRs
using f32x4  = __attribute__((ext_vector_type(4))) float;

typedef unsigned int uint32;

static __device__ __forceinline__ unsigned short f2bf(float f) {  // RNE f32->bf16
    uint32 u = __float_as_uint(f);
    u += 0x7fffu + ((u >> 16) & 1u);
    return (unsigned short)(u >> 16);
}
static __device__ __forceinline__ uint32 pk2(float a, float b) {
    return ((uint32)f2bf(a)) | (((uint32)f2bf(b)) << 16);
}
static __device__ __forceinline__ float bflo(uint32 u) { return __uint_as_float(u << 16); }
static __device__ __forceinline__ float bfhi(uint32 u) { return __uint_as_float(u & 0xffff0000u); }

// ---------------------------------------------------------------------------
// Stage 0: weight prep. wtab[(widx*64+lane)*8+j] = bf16(W1[row][col+j]);
// widx=(wave*4+ot)*4+ks; o=wave*64+ot*16+(lane&15); row=o&127;
// col=(o>=128?128:0)+ks*32+(lane>>4)*8.  bias256[o] = o<128 ? b1[o] : 0.
// ---------------------------------------------------------------------------
__global__ __launch_bounds__(256) void prep_kernel(
    const float* __restrict__ W1,
    const float* __restrict__ b1,
    unsigned short* __restrict__ wtab,
    float* __restrict__ bias256)
{
    const int idx  = blockIdx.x * 256 + threadIdx.x;  // 0..4095
    const int widx = idx >> 6;
    const int lane = idx & 63;
    const int wave = widx >> 4;
    const int ot   = (widx >> 2) & 3;
    const int ks   = widx & 3;
    const int o    = wave * 64 + ot * 16 + (lane & 15);
    const int row  = o & 127;
    const int col  = ((o >= 128) ? 128 : 0) + ks * 32 + (lane >> 4) * 8;
    const float* p = W1 + row * 256 + col;
    float4 f0 = *(const float4*)p;
    float4 f1 = *(const float4*)(p + 4);
    uint4 st;
    st.x = pk2(f0.x, f0.y);
    st.y = pk2(f0.z, f0.w);
    st.z = pk2(f1.x, f1.y);
    st.w = pk2(f1.z, f1.w);
    *(uint4*)(wtab + (size_t)idx * 8) = st;

    if (idx < 256) bias256[idx] = (idx < 128) ? b1[idx] : 0.0f;
}

// ---------------------------------------------------------------------------
// Stage 1 (v3): 64 nodes x 256 outputs per block, single barrier.
// mfma_f32_16x16x32_bf16 (m89): A[m=lane&15][k=quad*8+j], B[k=quad*8+j][n=lane&15],
// C/D col=lane&15 (node-within-tile), row=quad*4+reg (output).
// LDS tile: 64 rows x 128 ushort (16 KB), even-XOR swizzle (<=2-way banks).
// ---------------------------------------------------------------------------
__global__ __launch_bounds__(256) void node_stage_v3_kernel(
    const float* __restrict__ h,             // [N,128]
    const unsigned short* __restrict__ wtab, // [64*64*8]
    const float* __restrict__ bias256,       // [256]
    unsigned short* __restrict__ AB,         // [N,256] out
    int N)
{
    __shared__ unsigned short hs[64 * 128];  // 16 KB

    const int t    = threadIdx.x;
    const int lane = t & 63;
    const int wave = t >> 6;
    const int c    = lane & 15;
    const int q    = lane >> 4;

    short8 vfrag[4][4];
    float4 bias[4];
#pragma unroll
    for (int ot = 0; ot < 4; ++ot) {
#pragma unroll
        for (int ks = 0; ks < 4; ++ks) {
            int widx = (wave * 4 + ot) * 4 + ks;
            vfrag[ot][ks] = *(const short8*)(wtab + ((size_t)widx * 64 + lane) * 8);
        }
        bias[ot] = *(const float4*)(bias256 + wave * 64 + ot * 16 + q * 4);
    }

    const int n0 = blockIdx.x * 64;

    float4 g[8];
#pragma unroll
    for (int j = 0; j < 8; ++j) {
        int e4 = j * 256 + t;
        int rl = e4 >> 5;
        int grow = n0 + rl;
        if (grow >= N) grow = N - 1;              // tail clamp (dup read, unstored)
        g[j] = *(const float4*)(h + (size_t)grow * HID + (e4 & 31) * 4);
    }
#pragma unroll
    for (int j = 0; j < 8; ++j) {
        int e4 = j * 256 + t;
        int rl = e4 >> 5;
        int u  = e4 & 31;
        uint2 w2;
        w2.x = pk2(g[j].x, g[j].y);
        w2.y = pk2(g[j].z, g[j].w);
        *(uint2*)(hs + rl * 128 + ((u ^ ((rl & 15) << 1)) << 2)) = w2;
    }
    __syncthreads();  // the ONLY barrier

    f32x4 acc[4][4];  // [nt][ot]
#pragma unroll
    for (int nt = 0; nt < 4; ++nt)
#pragma unroll
        for (int ot = 0; ot < 4; ++ot) acc[nt][ot] = (f32x4){0.f, 0.f, 0.f, 0.f};

#pragma unroll
    for (int ks = 0; ks < 4; ++ks) {
        short8 hfrag[4];
#pragma unroll
        for (int nt = 0; nt < 4; ++nt) {
            int r  = nt * 16 + c;
            int u0 = ks * 8 + q * 2;                     // even
            hfrag[nt] = *(const short8*)(hs + r * 128 + ((u0 ^ (c << 1)) << 2));
        }
#pragma unroll
        for (int nt = 0; nt < 4; ++nt)
#pragma unroll
            for (int ot = 0; ot < 4; ++ot)
                acc[nt][ot] = __builtin_amdgcn_mfma_f32_16x16x32_bf16(
                    vfrag[ot][ks], hfrag[nt], acc[nt][ot], 0, 0, 0);
    }

#pragma unroll
    for (int nt = 0; nt < 4; ++nt) {
        const int node = n0 + nt * 16 + c;
        if (node < N) {
#pragma unroll
            for (int ot = 0; ot < 4; ++ot) {
                int o_base = wave * 64 + ot * 16 + q * 4;
                uint2 st;
                st.x = pk2(acc[nt][ot][0] + bias[ot].x, acc[nt][ot][1] + bias[ot].y);
                st.y = pk2(acc[nt][ot][2] + bias[ot].z, acc[nt][ot][3] + bias[ot].w);
                *(uint2*)(AB + (size_t)node * 256 + o_base) = st;
            }
        }
    }
}

// ---------------------------------------------------------------------------
// Stage 1 (v1 fallback, ws only fits AB): in-kernel weight conversion.
// ---------------------------------------------------------------------------
__global__ __launch_bounds__(256) void node_stage_kernel(
    const float* __restrict__ h,
    const float* __restrict__ W1,
    const float* __restrict__ b1,
    unsigned short* __restrict__ AB,
    int N)
{
    __shared__ unsigned short hsb[16 * 256];

    const int t    = threadIdx.x;
    const int lane = t & 63;
    const int wave = t >> 6;
    const int c    = lane & 15;
    const int q    = lane >> 4;

    short8 vfrag[4][4];
    float  bias[4][4];
#pragma unroll
    for (int ot = 0; ot < 4; ++ot) {
#pragma unroll
        for (int ks = 0; ks < 4; ++ks) {
            int o   = wave * 64 + ot * 16 + c;
            int row = o & 127;
            int col = ((o >= 128) ? 128 : 0) + ks * 32 + q * 8;
            const float* p = W1 + row * 256 + col;
            float4 f0 = *(const float4*)p;
            float4 f1 = *(const float4*)(p + 4);
            short8 v;
            v[0] = (short)f2bf(f0.x); v[1] = (short)f2bf(f0.y);
            v[2] = (short)f2bf(f0.z); v[3] = (short)f2bf(f0.w);
            v[4] = (short)f2bf(f1.x); v[5] = (short)f2bf(f1.y);
            v[6] = (short)f2bf(f1.z); v[7] = (short)f2bf(f1.w);
            vfrag[ot][ks] = v;
        }
#pragma unroll
        for (int r = 0; r < 4; ++r) {
            int o = wave * 64 + ot * 16 + q * 4 + r;
            bias[ot][r] = (o < 128) ? b1[o] : 0.0f;
        }
    }

    const int sr = t >> 4;
    const int sj = t & 15;
    const int ntiles = N >> 4;
    for (int tile = blockIdx.x; tile < ntiles; tile += gridDim.x) {
        int n0 = tile * 16;
        {
            const float* p = h + (size_t)(n0 + sr) * HID + sj * 8;
            float4 f0 = *(const float4*)p;
            float4 f1 = *(const float4*)(p + 4);
            uint4 st;
            st.x = pk2(f0.x, f0.y);
            st.y = pk2(f0.z, f0.w);
            st.z = pk2(f1.x, f1.y);
            st.w = pk2(f1.z, f1.w);
            *(uint4*)(hsb + sr * 256 + ((sj ^ sr) * 8)) = st;
        }
        __syncthreads();

        short8 hfrag[4];
#pragma unroll
        for (int ks = 0; ks < 4; ++ks) {
            int blk = (ks * 4 + q) ^ c;
            hfrag[ks] = *(const short8*)(hsb + c * 256 + blk * 8);
        }

        f32x4 acc[4];
#pragma unroll
        for (int ot = 0; ot < 4; ++ot) acc[ot] = (f32x4){0.f, 0.f, 0.f, 0.f};
#pragma unroll
        for (int ks = 0; ks < 4; ++ks)
#pragma unroll
            for (int ot = 0; ot < 4; ++ot)
                acc[ot] = __builtin_amdgcn_mfma_f32_16x16x32_bf16(
                    vfrag[ot][ks], hfrag[ks], acc[ot], 0, 0, 0);

        const int node = n0 + c;
#pragma unroll
        for (int ot = 0; ot < 4; ++ot) {
            int o_base = wave * 64 + ot * 16 + q * 4;
            uint2 st;
            st.x = pk2(acc[ot][0] + bias[ot][0], acc[ot][1] + bias[ot][1]);
            st.y = pk2(acc[ot][2] + bias[ot][2], acc[ot][3] + bias[ot][3]);
            *(uint2*)(AB + (size_t)node * 256 + o_base) = st;
        }
        __syncthreads();
    }
}

// ---------------------------------------------------------------------------
// Stage 2 (v4): 16 edges/wave = 2 edges per 8-lane group. All 8 gathers
// (4 per edge) issued before any unpack -> 8 outstanding 16B loads/lane.
// W2 held in registers shared by both edges. Reduce = 3 xor-shuffles for both
// accumulators; tails stored with 8 active lanes (coalesced dwords).
// ---------------------------------------------------------------------------
__global__ __launch_bounds__(256) void edge_stage_kernel(
    const unsigned short* __restrict__ AB,  // [N,256] bf16 bits
    const int* __restrict__ src,
    const int* __restrict__ dst,
    const float* __restrict__ W2,   // [128]
    const float* __restrict__ b2,
    const float* __restrict__ W3,
    const float* __restrict__ b3,
    float* __restrict__ out,        // [E]
    int E)
{
    const int lane = threadIdx.x & 63;
    const int wave = threadIdx.x >> 6;
    const int sub  = lane & 7;      // lane within edge group (8)
    const int eg   = lane >> 3;     // edge-group slot 0..7
    const int base = blockIdx.x * 64 + wave * 16;
    const int e0   = base + eg;
    const int e1   = base + 8 + eg;
    if (base >= E) return;
    const int ee0 = (e0 < E) ? e0 : (E - 1);   // clamp: safe dup read, store guarded
    const int ee1 = (e1 < E) ? e1 : (E - 1);

    const int s0 = src[ee0];
    const int d0 = dst[ee0];
    const int s1 = src[ee1];
    const int d1 = dst[ee1];

    const unsigned short* pa0 = AB + (size_t)s0 * 256 + sub * 16;
    const unsigned short* pb0 = AB + (size_t)d0 * 256 + 128 + sub * 16;
    const unsigned short* pa1 = AB + (size_t)s1 * 256 + sub * 16;
    const unsigned short* pb1 = AB + (size_t)d1 * 256 + 128 + sub * 16;

    // 8 independent 16B gathers, all issued before first use.
    const uint4 a00 = *(const uint4*)pa0;
    const uint4 a01 = *(const uint4*)(pa0 + 8);
    const uint4 b00 = *(const uint4*)pb0;
    const uint4 b01 = *(const uint4*)(pb0 + 8);
    const uint4 a10 = *(const uint4*)pa1;
    const uint4 a11 = *(const uint4*)(pa1 + 8);
    const uint4 b10 = *(const uint4*)pb1;
    const uint4 b11 = *(const uint4*)(pb1 + 8);

    const float4 w0  = *(const float4*)(W2 + sub * 16);
    const float4 w1  = *(const float4*)(W2 + sub * 16 + 4);
    const float4 w2v = *(const float4*)(W2 + sub * 16 + 8);
    const float4 w3v = *(const float4*)(W2 + sub * 16 + 12);

#define ACC8(p, ua, ub, wa, wb)                                   \
    {                                                             \
        float t0 = fmaxf(bflo(ua.x) + bflo(ub.x), 0.0f);          \
        float t1 = fmaxf(bfhi(ua.x) + bfhi(ub.x), 0.0f);          \
        float t2 = fmaxf(bflo(ua.y) + bflo(ub.y), 0.0f);          \
        float t3 = fmaxf(bfhi(ua.y) + bfhi(ub.y), 0.0f);          \
        float t4 = fmaxf(bflo(ua.z) + bflo(ub.z), 0.0f);          \
        float t5 = fmaxf(bfhi(ua.z) + bfhi(ub.z), 0.0f);          \
        float t6 = fmaxf(bflo(ua.w) + bflo(ub.w), 0.0f);          \
        float t7 = fmaxf(bfhi(ua.w) + bfhi(ub.w), 0.0f);          \
        p = fmaf(t0, wa.x, p);                                    \
        p = fmaf(t1, wa.y, p);                                    \
        p = fmaf(t2, wa.z, p);                                    \
        p = fmaf(t3, wa.w, p);                                    \
        p = fmaf(t4, wb.x, p);                                    \
        p = fmaf(t5, wb.y, p);                                    \
        p = fmaf(t6, wb.z, p);                                    \
        p = fmaf(t7, wb.w, p);                                    \
    }

    float p0 = 0.0f, p1 = 0.0f;
    ACC8(p0, a00, b00, w0, w1);
    ACC8(p0, a01, b01, w2v, w3v);
    ACC8(p1, a10, b10, w0, w1);
    ACC8(p1, a11, b11, w2v, w3v);
#undef ACC8

#pragma unroll
    for (int m = 4; m >= 1; m >>= 1) {
        p0 += __shfl_xor(p0, m, 64);
        p1 += __shfl_xor(p1, m, 64);
    }

    if (sub == 0) {
        const float bb2 = b2[0], ww3 = W3[0], bb3 = b3[0];
        if (e0 < E) {
            float y2 = fmaxf(p0 + bb2, 0.0f);
            float y3 = fmaxf(ww3 * y2 + bb3, 0.0f);
            out[e0] = 1.0f / (1.0f + __expf(-y3));
        }
        if (e1 < E) {
            float y2 = fmaxf(p1 + bb2, 0.0f);
            float y3 = fmaxf(ww3 * y2 + bb3, 0.0f);
            out[e1] = 1.0f / (1.0f + __expf(-y3));
        }
    }
}

// ---------------------------------------------------------------------------
// Fallback (ws too small for AB): direct per-edge MLP, fp32. Correct, slow.
// ---------------------------------------------------------------------------
__global__ __launch_bounds__(256) void edge_direct_kernel(
    const float* __restrict__ h,
    const int* __restrict__ src,
    const int* __restrict__ dst,
    const float* __restrict__ W1,
    const float* __restrict__ b1,
    const float* __restrict__ W2,
    const float* __restrict__ b2,
    const float* __restrict__ W3,
    const float* __restrict__ b3,
    float* __restrict__ out,
    int E)
{
    __shared__ float x[256];
    __shared__ float red[4];
    const int e = blockIdx.x;
    if (e >= E) return;
    const int t = threadIdx.x;
    const int s = src[e];
    const int d = dst[e];

    if (t < 128) x[t] = h[(size_t)s * HID + t];
    else         x[t] = h[(size_t)d * HID + (t - 128)];
    __syncthreads();

    float contrib = 0.0f;
    if (t < 128) {
        float acc = b1[t];
        const float* wr = W1 + t * 256;
        for (int k = 0; k < 256; ++k) acc = fmaf(wr[k], x[k], acc);
        contrib = fmaxf(acc, 0.0f) * W2[t];
    }
#pragma unroll
    for (int m = 32; m >= 1; m >>= 1) contrib += __shfl_xor(contrib, m, 64);
    if ((t & 63) == 0) red[t >> 6] = contrib;
    __syncthreads();
    if (t == 0) {
        float p = red[0] + red[1] + red[2] + red[3];
        float y2 = fmaxf(p + b2[0], 0.0f);
        float y3 = fmaxf(W3[0] * y2 + b3[0], 0.0f);
        out[e] = 1.0f / (1.0f + __expf(-y3));
    }
}

extern "C" void kernel_launch(void* const* d_in, const int* in_sizes, int n_in,
                              void* d_out, int out_size, void* d_ws, size_t ws_size,
                              hipStream_t stream) {
    const float* h   = (const float*)d_in[0];
    const int*   src = (const int*)d_in[1];
    const int*   dst = (const int*)d_in[2];
    const float* W1  = (const float*)d_in[3];
    const float* b1  = (const float*)d_in[4];
    const float* W2  = (const float*)d_in[5];
    const float* b2  = (const float*)d_in[6];
    const float* W3  = (const float*)d_in[7];
    const float* b3  = (const float*)d_in[8];
    float* out = (float*)d_out;

    const int N = in_sizes[0] / HID;   // 100000
    const int E = in_sizes[1];         // 500000

    const size_t ab_bytes   = (size_t)N * 256 * sizeof(unsigned short);
    const size_t wtab_off   = (ab_bytes + 255) & ~(size_t)255;
    const size_t wtab_bytes = (size_t)64 * 64 * 8 * sizeof(unsigned short);  // 64 KB
    const size_t bias_off   = wtab_off + wtab_bytes;
    const size_t need_v2    = bias_off + 256 * sizeof(float);

    if (need_v2 <= ws_size) {
        unsigned short* AB   = (unsigned short*)d_ws;
        unsigned short* wtab = (unsigned short*)((char*)d_ws + wtab_off);
        float* bias256       = (float*)((char*)d_ws + bias_off);
        prep_kernel<<<16, 256, 0, stream>>>(W1, b1, wtab, bias256);
        const int nblocks = (N + 63) / 64;
        node_stage_v3_kernel<<<nblocks, 256, 0, stream>>>(h, wtab, bias256, AB, N);
        edge_stage_kernel<<<(E + 63) / 64, 256, 0, stream>>>(AB, src, dst, W2, b2, W3, b3, out, E);
    } else if (ab_bytes <= ws_size) {
        unsigned short* AB = (unsigned short*)d_ws;
        node_stage_kernel<<<1563, 256, 0, stream>>>(h, W1, b1, AB, N);
        edge_stage_kernel<<<(E + 63) / 64, 256, 0, stream>>>(AB, src, dst, W2, b2, W3, b3, out, E);
    } else {
        edge_direct_kernel<<<E, 256, 0, stream>>>(h, src, dst, W1, b1, W2, b2, W3, b3, out, E);
    }
}

// Round 9
// 129.688 us; speedup vs baseline: 1.1898x; 1.1787x over previous
//
#include <hip/hip_runtime.h>
#include <hip/hip_bf16.h>

// h:[N,128] f32, src/dst:[E] i32, W1:[128,256] f32, b1:[128] f32, W2:[1,128] f32,
// b2,W3,b3: scalars f32  -> out:[E] f32
// Factorization: W1@concat(h[s],h[d]) = W1[:,:128]@h[s] + W1[:,128:]@h[d]
// Stage 0 (prep): W1 f32 -> fragment-ordered bf16 table (64 KB) + bias256 f32.
// Stage 1 (node, MFMA bf16): 64 nodes/block; epilogue quantizes A/B halves to
//   INT8 with per-node-half scales (AB8:[N,256] i8 = 25.6 MB, scales float2[N]).
//   One half-row = 128 B = ONE cache line -> halves edge gather line traffic.
//   R8 bugfix: LDS->global copy-out now covers all 64 rows (was 16 -> 75% of
//   nodes left poisoned, absmax 0.35).
// Stage 2 (edge): 16 edges/wave, 8 lanes/edge; per lane 2 uint4 int8 gathers
//   per edge + broadcast float2 scale loads (L2-hot 800 KB array).

#define HID 128

using short8 = __attribute__((ext_vector_type(8))) short;  // 8 bf16 = 4 VGPRs
using f32x4  = __attribute__((ext_vector_type(4))) float;

typedef unsigned int uint32;

static __device__ __forceinline__ unsigned short f2bf(float f) {  // RNE f32->bf16
    uint32 u = __float_as_uint(f);
    u += 0x7fffu + ((u >> 16) & 1u);
    return (unsigned short)(u >> 16);
}
static __device__ __forceinline__ uint32 pk2(float a, float b) {
    return ((uint32)f2bf(a)) | (((uint32)f2bf(b)) << 16);
}
static __device__ __forceinline__ float bflo(uint32 u) { return __uint_as_float(u << 16); }
static __device__ __forceinline__ float bfhi(uint32 u) { return __uint_as_float(u & 0xffff0000u); }
static __device__ __forceinline__ float sb2f(uint32 u, int k) {  // signed byte k -> float
    return (float)(signed char)((u >> (k * 8)) & 0xffu);
}

// ---------------------------------------------------------------------------
// Stage 0: weight prep. wtab[(widx*64+lane)*8+j] = bf16(W1[row][col+j]);
// widx=(wave*4+ot)*4+ks; o=wave*64+ot*16+(lane&15); row=o&127;
// col=(o>=128?128:0)+ks*32+(lane>>4)*8.  bias256[o] = o<128 ? b1[o] : 0.
// ---------------------------------------------------------------------------
__global__ __launch_bounds__(256) void prep_kernel(
    const float* __restrict__ W1,
    const float* __restrict__ b1,
    unsigned short* __restrict__ wtab,
    float* __restrict__ bias256)
{
    const int idx  = blockIdx.x * 256 + threadIdx.x;  // 0..4095
    const int widx = idx >> 6;
    const int lane = idx & 63;
    const int wave = widx >> 4;
    const int ot   = (widx >> 2) & 3;
    const int ks   = widx & 3;
    const int o    = wave * 64 + ot * 16 + (lane & 15);
    const int row  = o & 127;
    const int col  = ((o >= 128) ? 128 : 0) + ks * 32 + (lane >> 4) * 8;
    const float* p = W1 + row * 256 + col;
    float4 f0 = *(const float4*)p;
    float4 f1 = *(const float4*)(p + 4);
    uint4 st;
    st.x = pk2(f0.x, f0.y);
    st.y = pk2(f0.z, f0.w);
    st.z = pk2(f1.x, f1.y);
    st.w = pk2(f1.z, f1.w);
    *(uint4*)(wtab + (size_t)idx * 8) = st;

    if (idx < 256) bias256[idx] = (idx < 128) ? b1[idx] : 0.0f;
}

// ---------------------------------------------------------------------------
// Stage 1 (int8 out): 64 nodes x 256 outputs per block.
// mfma_f32_16x16x32_bf16 (m89): A[m=lane&15][k=quad*8+j], B[k=quad*8+j][n=lane&15],
// C/D col=lane&15 (node-in-tile), row=quad*4+reg (output channel).
// Epilogue: per-(node,half) absmax (2 shuffles + LDS cross-wave max), quantize
// q=rn(v*127/max), pack 4/uint, stage in XOR-swizzled LDS, store coalesced
// (4 row-groups x 16 rows).  scales[n] = (maxA/127, maxB/127).
// ---------------------------------------------------------------------------
__global__ __launch_bounds__(256) void node_stage_i8_kernel(
    const float* __restrict__ h,             // [N,128]
    const unsigned short* __restrict__ wtab, // [64*64*8]
    const float* __restrict__ bias256,       // [256]
    signed char* __restrict__ AB8,           // [N,256] int8 out
    float2* __restrict__ scales,             // [N] (scaleA, scaleB)
    int N)
{
    __shared__ unsigned short hs[64 * 128];  // 16 KB input tile
    __shared__ uint32 ab8u[64 * 64];         // 16 KB quantized output tile
    __shared__ float  wmax[4][4][16];        // [wave][nt][c]

    const int t    = threadIdx.x;
    const int lane = t & 63;
    const int wave = t >> 6;
    const int c    = lane & 15;
    const int q    = lane >> 4;

    short8 vfrag[4][4];
    float4 bias[4];
#pragma unroll
    for (int ot = 0; ot < 4; ++ot) {
#pragma unroll
        for (int ks = 0; ks < 4; ++ks) {
            int widx = (wave * 4 + ot) * 4 + ks;
            vfrag[ot][ks] = *(const short8*)(wtab + ((size_t)widx * 64 + lane) * 8);
        }
        bias[ot] = *(const float4*)(bias256 + wave * 64 + ot * 16 + q * 4);
    }

    const int n0 = blockIdx.x * 64;

    // stage h tile (f32 -> bf16), even-XOR swizzled 8B units
    float4 g[8];
#pragma unroll
    for (int j = 0; j < 8; ++j) {
        int e4 = j * 256 + t;
        int rl = e4 >> 5;
        int grow = n0 + rl;
        if (grow >= N) grow = N - 1;              // tail clamp (dup read, store guarded)
        g[j] = *(const float4*)(h + (size_t)grow * HID + (e4 & 31) * 4);
    }
#pragma unroll
    for (int j = 0; j < 8; ++j) {
        int e4 = j * 256 + t;
        int rl = e4 >> 5;
        int u  = e4 & 31;
        uint2 w2;
        w2.x = pk2(g[j].x, g[j].y);
        w2.y = pk2(g[j].z, g[j].w);
        *(uint2*)(hs + rl * 128 + ((u ^ ((rl & 15) << 1)) << 2)) = w2;
    }
    __syncthreads();

    f32x4 acc[4][4];  // [nt][ot]
#pragma unroll
    for (int nt = 0; nt < 4; ++nt)
#pragma unroll
        for (int ot = 0; ot < 4; ++ot) acc[nt][ot] = (f32x4){0.f, 0.f, 0.f, 0.f};

#pragma unroll
    for (int ks = 0; ks < 4; ++ks) {
        short8 hfrag[4];
#pragma unroll
        for (int nt = 0; nt < 4; ++nt) {
            int r  = nt * 16 + c;
            int u0 = ks * 8 + q * 2;
            hfrag[nt] = *(const short8*)(hs + r * 128 + ((u0 ^ (c << 1)) << 2));
        }
#pragma unroll
        for (int nt = 0; nt < 4; ++nt)
#pragma unroll
            for (int ot = 0; ot < 4; ++ot)
                acc[nt][ot] = __builtin_amdgcn_mfma_f32_16x16x32_bf16(
                    vfrag[ot][ks], hfrag[nt], acc[nt][ot], 0, 0, 0);
    }

    // bias add in place + per-lane per-nt absmax
    float lmax[4];
#pragma unroll
    for (int nt = 0; nt < 4; ++nt) {
        float m = 0.0f;
#pragma unroll
        for (int ot = 0; ot < 4; ++ot) {
            acc[nt][ot][0] += bias[ot].x;
            acc[nt][ot][1] += bias[ot].y;
            acc[nt][ot][2] += bias[ot].z;
            acc[nt][ot][3] += bias[ot].w;
            m = fmaxf(m, fabsf(acc[nt][ot][0]));
            m = fmaxf(m, fabsf(acc[nt][ot][1]));
            m = fmaxf(m, fabsf(acc[nt][ot][2]));
            m = fmaxf(m, fabsf(acc[nt][ot][3]));
        }
        // combine across the 4 q-lanes holding the same node column
        m = fmaxf(m, __shfl_xor(m, 16, 64));
        m = fmaxf(m, __shfl_xor(m, 32, 64));
        lmax[nt] = m;
    }
    if (q == 0) {
#pragma unroll
        for (int nt = 0; nt < 4; ++nt) wmax[wave][nt][c] = lmax[nt];
    }
    __syncthreads();

    // this wave's half: waves 0,1 -> A (o<128); waves 2,3 -> B
    const int hw = (wave >> 1) * 2;
    float inv[4];
#pragma unroll
    for (int nt = 0; nt < 4; ++nt) {
        float m = fmaxf(wmax[hw][nt][c], wmax[hw + 1][nt][c]);
        inv[nt] = (m > 0.0f) ? (127.0f / m) : 0.0f;
    }

    // scales store (one thread per node)
    if (t < 64) {
        int nt2 = t >> 4, c2 = t & 15;
        if (n0 + t < N) {
            float ma = fmaxf(wmax[0][nt2][c2], wmax[1][nt2][c2]);
            float mb = fmaxf(wmax[2][nt2][c2], wmax[3][nt2][c2]);
            scales[n0 + t] = make_float2(ma * (1.0f / 127.0f), mb * (1.0f / 127.0f));
        }
    }

    // quantize + stage in LDS (uint index XOR-swizzled by row bits 3..5)
#pragma unroll
    for (int nt = 0; nt < 4; ++nt) {
        const int rowl = nt * 16 + c;
#pragma unroll
        for (int ot = 0; ot < 4; ++ot) {
            int q0 = __float2int_rn(acc[nt][ot][0] * inv[nt]);
            int q1 = __float2int_rn(acc[nt][ot][1] * inv[nt]);
            int q2 = __float2int_rn(acc[nt][ot][2] * inv[nt]);
            int q3 = __float2int_rn(acc[nt][ot][3] * inv[nt]);
            uint32 packed = (uint32)(q0 & 255) | ((uint32)(q1 & 255) << 8) |
                            ((uint32)(q2 & 255) << 16) | ((uint32)(q3 & 255) << 24);
            int uidx = wave * 16 + ot * 4 + q;
            ab8u[rowl * 64 + (uidx ^ ((rowl & 7) << 3))] = packed;
        }
    }
    __syncthreads();

    // coalesced store: 4 row-groups x (16 rows x 16 threads x 16B) covers all
    // 64 rows (R8 bugfix: previously only rows 0..15 were stored).
#pragma unroll
    for (int j = 0; j < 4; ++j) {
        const int rowl = j * 16 + (t >> 4);
        const int grow = n0 + rowl;
        if (grow < N) {
            const int u0 = 4 * (t & 15);
            uint4 st;
            st.x = ab8u[rowl * 64 + ((u0 + 0) ^ ((rowl & 7) << 3))];
            st.y = ab8u[rowl * 64 + ((u0 + 1) ^ ((rowl & 7) << 3))];
            st.z = ab8u[rowl * 64 + ((u0 + 2) ^ ((rowl & 7) << 3))];
            st.w = ab8u[rowl * 64 + ((u0 + 3) ^ ((rowl & 7) << 3))];
            *(uint4*)(AB8 + (size_t)grow * 256 + (t & 15) * 16) = st;
        }
    }
}

// ---------------------------------------------------------------------------
// Stage 2 (int8): 16 edges/wave = 2 per 8-lane group. Per lane per edge:
// one uint4 from A-half (one 128B line/row) + one from B-half + broadcast
// float2 scale loads. 4 gathers + 4 scale loads issued before any unpack.
// ---------------------------------------------------------------------------
__global__ __launch_bounds__(256) void edge_stage_i8_kernel(
    const signed char* __restrict__ AB8,   // [N,256] int8
    const float2* __restrict__ scales,     // [N]
    const int* __restrict__ src,
    const int* __restrict__ dst,
    const float* __restrict__ W2,   // [128]
    const float* __restrict__ b2,
    const float* __restrict__ W3,
    const float* __restrict__ b3,
    float* __restrict__ out,        // [E]
    int E)
{
    const int lane = threadIdx.x & 63;
    const int wave = threadIdx.x >> 6;
    const int sub  = lane & 7;
    const int eg   = lane >> 3;
    const int base = blockIdx.x * 64 + wave * 16;
    const int e0   = base + eg;
    const int e1   = base + 8 + eg;
    if (base >= E) return;
    const int ee0 = (e0 < E) ? e0 : (E - 1);
    const int ee1 = (e1 < E) ? e1 : (E - 1);

    const int s0 = src[ee0];
    const int d0 = dst[ee0];
    const int s1 = src[ee1];
    const int d1 = dst[ee1];

    // 4 independent 16B gathers + 4 broadcast scale loads
    const uint4 a0 = *(const uint4*)(AB8 + (size_t)s0 * 256 + sub * 16);
    const uint4 b0 = *(const uint4*)(AB8 + (size_t)d0 * 256 + 128 + sub * 16);
    const uint4 a1 = *(const uint4*)(AB8 + (size_t)s1 * 256 + sub * 16);
    const uint4 b1 = *(const uint4*)(AB8 + (size_t)d1 * 256 + 128 + sub * 16);
    const float sa0 = scales[s0].x;
    const float sb0 = scales[d0].y;
    const float sa1 = scales[s1].x;
    const float sb1 = scales[d1].y;

    const float4 w0  = *(const float4*)(W2 + sub * 16);
    const float4 w1  = *(const float4*)(W2 + sub * 16 + 4);
    const float4 w2v = *(const float4*)(W2 + sub * 16 + 8);
    const float4 w3v = *(const float4*)(W2 + sub * 16 + 12);

#define ACCU4(p, ua, ub, wv, sa, sb)                                          \
    {                                                                         \
        float t0 = fmaxf(fmaf(sb2f(ua, 0), sa, sb2f(ub, 0) * sb), 0.0f);      \
        float t1 = fmaxf(fmaf(sb2f(ua, 1), sa, sb2f(ub, 1) * sb), 0.0f);      \
        float t2 = fmaxf(fmaf(sb2f(ua, 2), sa, sb2f(ub, 2) * sb), 0.0f);      \
        float t3 = fmaxf(fmaf(sb2f(ua, 3), sa, sb2f(ub, 3) * sb), 0.0f);      \
        p = fmaf(t0, wv.x, p);                                                \
        p = fmaf(t1, wv.y, p);                                                \
        p = fmaf(t2, wv.z, p);                                                \
        p = fmaf(t3, wv.w, p);                                                \
    }

    float p0 = 0.0f, p1 = 0.0f;
    ACCU4(p0, a0.x, b0.x, w0, sa0, sb0);
    ACCU4(p0, a0.y, b0.y, w1, sa0, sb0);
    ACCU4(p0, a0.z, b0.z, w2v, sa0, sb0);
    ACCU4(p0, a0.w, b0.w, w3v, sa0, sb0);
    ACCU4(p1, a1.x, b1.x, w0, sa1, sb1);
    ACCU4(p1, a1.y, b1.y, w1, sa1, sb1);
    ACCU4(p1, a1.z, b1.z, w2v, sa1, sb1);
    ACCU4(p1, a1.w, b1.w, w3v, sa1, sb1);
#undef ACCU4

#pragma unroll
    for (int m = 4; m >= 1; m >>= 1) {
        p0 += __shfl_xor(p0, m, 64);
        p1 += __shfl_xor(p1, m, 64);
    }

    if (sub == 0) {
        const float bb2 = b2[0], ww3 = W3[0], bb3 = b3[0];
        if (e0 < E) {
            float y2 = fmaxf(p0 + bb2, 0.0f);
            float y3 = fmaxf(ww3 * y2 + bb3, 0.0f);
            out[e0] = 1.0f / (1.0f + __expf(-y3));
        }
        if (e1 < E) {
            float y2 = fmaxf(p1 + bb2, 0.0f);
            float y3 = fmaxf(ww3 * y2 + bb3, 0.0f);
            out[e1] = 1.0f / (1.0f + __expf(-y3));
        }
    }
}

// ---------------------------------------------------------------------------
// bf16 fallback path (ws fits AB bf16 but not int8 layout)
// ---------------------------------------------------------------------------
__global__ __launch_bounds__(256) void node_stage_kernel(
    const float* __restrict__ h,
    const float* __restrict__ W1,
    const float* __restrict__ b1,
    unsigned short* __restrict__ AB,
    int N)
{
    __shared__ unsigned short hsb[16 * 256];

    const int t    = threadIdx.x;
    const int lane = t & 63;
    const int wave = t >> 6;
    const int c    = lane & 15;
    const int q    = lane >> 4;

    short8 vfrag[4][4];
    float  bias[4][4];
#pragma unroll
    for (int ot = 0; ot < 4; ++ot) {
#pragma unroll
        for (int ks = 0; ks < 4; ++ks) {
            int o   = wave * 64 + ot * 16 + c;
            int row = o & 127;
            int col = ((o >= 128) ? 128 : 0) + ks * 32 + q * 8;
            const float* p = W1 + row * 256 + col;
            float4 f0 = *(const float4*)p;
            float4 f1 = *(const float4*)(p + 4);
            short8 v;
            v[0] = (short)f2bf(f0.x); v[1] = (short)f2bf(f0.y);
            v[2] = (short)f2bf(f0.z); v[3] = (short)f2bf(f0.w);
            v[4] = (short)f2bf(f1.x); v[5] = (short)f2bf(f1.y);
            v[6] = (short)f2bf(f1.z); v[7] = (short)f2bf(f1.w);
            vfrag[ot][ks] = v;
        }
#pragma unroll
        for (int r = 0; r < 4; ++r) {
            int o = wave * 64 + ot * 16 + q * 4 + r;
            bias[ot][r] = (o < 128) ? b1[o] : 0.0f;
        }
    }

    const int sr = t >> 4;
    const int sj = t & 15;
    const int ntiles = N >> 4;
    for (int tile = blockIdx.x; tile < ntiles; tile += gridDim.x) {
        int n0 = tile * 16;
        {
            const float* p = h + (size_t)(n0 + sr) * HID + sj * 8;
            float4 f0 = *(const float4*)p;
            float4 f1 = *(const float4*)(p + 4);
            uint4 st;
            st.x = pk2(f0.x, f0.y);
            st.y = pk2(f0.z, f0.w);
            st.z = pk2(f1.x, f1.y);
            st.w = pk2(f1.z, f1.w);
            *(uint4*)(hsb + sr * 256 + ((sj ^ sr) * 8)) = st;
        }
        __syncthreads();

        short8 hfrag[4];
#pragma unroll
        for (int ks = 0; ks < 4; ++ks) {
            int blk = (ks * 4 + q) ^ c;
            hfrag[ks] = *(const short8*)(hsb + c * 256 + blk * 8);
        }

        f32x4 acc[4];
#pragma unroll
        for (int ot = 0; ot < 4; ++ot) acc[ot] = (f32x4){0.f, 0.f, 0.f, 0.f};
#pragma unroll
        for (int ks = 0; ks < 4; ++ks)
#pragma unroll
            for (int ot = 0; ot < 4; ++ot)
                acc[ot] = __builtin_amdgcn_mfma_f32_16x16x32_bf16(
                    vfrag[ot][ks], hfrag[ks], acc[ot], 0, 0, 0);

        const int node = n0 + c;
#pragma unroll
        for (int ot = 0; ot < 4; ++ot) {
            int o_base = wave * 64 + ot * 16 + q * 4;
            uint2 st;
            st.x = pk2(acc[ot][0] + bias[ot][0], acc[ot][1] + bias[ot][1]);
            st.y = pk2(acc[ot][2] + bias[ot][2], acc[ot][3] + bias[ot][3]);
            *(uint2*)(AB + (size_t)node * 256 + o_base) = st;
        }
        __syncthreads();
    }
}

__global__ __launch_bounds__(256) void edge_stage_kernel(
    const unsigned short* __restrict__ AB,  // [N,256] bf16 bits
    const int* __restrict__ src,
    const int* __restrict__ dst,
    const float* __restrict__ W2,
    const float* __restrict__ b2,
    const float* __restrict__ W3,
    const float* __restrict__ b3,
    float* __restrict__ out,
    int E)
{
    const int lane = threadIdx.x & 63;
    const int wave = threadIdx.x >> 6;
    const int sub  = lane & 7;
    const int eg   = lane >> 3;
    const int base = blockIdx.x * 64 + wave * 16;
    const int e0   = base + eg;
    const int e1   = base + 8 + eg;
    if (base >= E) return;
    const int ee0 = (e0 < E) ? e0 : (E - 1);
    const int ee1 = (e1 < E) ? e1 : (E - 1);

    const int s0 = src[ee0];
    const int d0 = dst[ee0];
    const int s1 = src[ee1];
    const int d1 = dst[ee1];

    const unsigned short* pa0 = AB + (size_t)s0 * 256 + sub * 16;
    const unsigned short* pb0 = AB + (size_t)d0 * 256 + 128 + sub * 16;
    const unsigned short* pa1 = AB + (size_t)s1 * 256 + sub * 16;
    const unsigned short* pb1 = AB + (size_t)d1 * 256 + 128 + sub * 16;

    const uint4 a00 = *(const uint4*)pa0;
    const uint4 a01 = *(const uint4*)(pa0 + 8);
    const uint4 b00 = *(const uint4*)pb0;
    const uint4 b01 = *(const uint4*)(pb0 + 8);
    const uint4 a10 = *(const uint4*)pa1;
    const uint4 a11 = *(const uint4*)(pa1 + 8);
    const uint4 b10 = *(const uint4*)pb1;
    const uint4 b11 = *(const uint4*)(pb1 + 8);

    const float4 w0  = *(const float4*)(W2 + sub * 16);
    const float4 w1  = *(const float4*)(W2 + sub * 16 + 4);
    const float4 w2v = *(const float4*)(W2 + sub * 16 + 8);
    const float4 w3v = *(const float4*)(W2 + sub * 16 + 12);

#define ACC8(p, ua, ub, wa, wb)                                   \
    {                                                             \
        float t0 = fmaxf(bflo(ua.x) + bflo(ub.x), 0.0f);          \
        float t1 = fmaxf(bfhi(ua.x) + bfhi(ub.x), 0.0f);          \
        float t2 = fmaxf(bflo(ua.y) + bflo(ub.y), 0.0f);          \
        float t3 = fmaxf(bfhi(ua.y) + bfhi(ub.y), 0.0f);          \
        float t4 = fmaxf(bflo(ua.z) + bflo(ub.z), 0.0f);          \
        float t5 = fmaxf(bfhi(ua.z) + bfhi(ub.z), 0.0f);          \
        float t6 = fmaxf(bflo(ua.w) + bflo(ub.w), 0.0f);          \
        float t7 = fmaxf(bfhi(ua.w) + bfhi(ub.w), 0.0f);          \
        p = fmaf(t0, wa.x, p);                                    \
        p = fmaf(t1, wa.y, p);                                    \
        p = fmaf(t2, wa.z, p);                                    \
        p = fmaf(t3, wa.w, p);                                    \
        p = fmaf(t4, wb.x, p);                                    \
        p = fmaf(t5, wb.y, p);                                    \
        p = fmaf(t6, wb.z, p);                                    \
        p = fmaf(t7, wb.w, p);                                    \
    }

    float p0 = 0.0f, p1 = 0.0f;
    ACC8(p0, a00, b00, w0, w1);
    ACC8(p0, a01, b01, w2v, w3v);
    ACC8(p1, a10, b10, w0, w1);
    ACC8(p1, a11, b11, w2v, w3v);
#undef ACC8

#pragma unroll
    for (int m = 4; m >= 1; m >>= 1) {
        p0 += __shfl_xor(p0, m, 64);
        p1 += __shfl_xor(p1, m, 64);
    }

    if (sub == 0) {
        const float bb2 = b2[0], ww3 = W3[0], bb3 = b3[0];
        if (e0 < E) {
            float y2 = fmaxf(p0 + bb2, 0.0f);
            float y3 = fmaxf(ww3 * y2 + bb3, 0.0f);
            out[e0] = 1.0f / (1.0f + __expf(-y3));
        }
        if (e1 < E) {
            float y2 = fmaxf(p1 + bb2, 0.0f);
            float y3 = fmaxf(ww3 * y2 + bb3, 0.0f);
            out[e1] = 1.0f / (1.0f + __expf(-y3));
        }
    }
}

// ---------------------------------------------------------------------------
// Last-resort fallback: direct per-edge MLP, fp32.
// ---------------------------------------------------------------------------
__global__ __launch_bounds__(256) void edge_direct_kernel(
    const float* __restrict__ h,
    const int* __restrict__ src,
    const int* __restrict__ dst,
    const float* __restrict__ W1,
    const float* __restrict__ b1,
    const float* __restrict__ W2,
    const float* __restrict__ b2,
    const float* __restrict__ W3,
    const float* __restrict__ b3,
    float* __restrict__ out,
    int E)
{
    __shared__ float x[256];
    __shared__ float red[4];
    const int e = blockIdx.x;
    if (e >= E) return;
    const int t = threadIdx.x;
    const int s = src[e];
    const int d = dst[e];

    if (t < 128) x[t] = h[(size_t)s * HID + t];
    else         x[t] = h[(size_t)d * HID + (t - 128)];
    __syncthreads();

    float contrib = 0.0f;
    if (t < 128) {
        float acc = b1[t];
        const float* wr = W1 + t * 256;
        for (int k = 0; k < 256; ++k) acc = fmaf(wr[k], x[k], acc);
        contrib = fmaxf(acc, 0.0f) * W2[t];
    }
#pragma unroll
    for (int m = 32; m >= 1; m >>= 1) contrib += __shfl_xor(contrib, m, 64);
    if ((t & 63) == 0) red[t >> 6] = contrib;
    __syncthreads();
    if (t == 0) {
        float p = red[0] + red[1] + red[2] + red[3];
        float y2 = fmaxf(p + b2[0], 0.0f);
        float y3 = fmaxf(W3[0] * y2 + b3[0], 0.0f);
        out[e] = 1.0f / (1.0f + __expf(-y3));
    }
}

extern "C" void kernel_launch(void* const* d_in, const int* in_sizes, int n_in,
                              void* d_out, int out_size, void* d_ws, size_t ws_size,
                              hipStream_t stream) {
    const float* h   = (const float*)d_in[0];
    const int*   src = (const int*)d_in[1];
    const int*   dst = (const int*)d_in[2];
    const float* W1  = (const float*)d_in[3];
    const float* b1  = (const float*)d_in[4];
    const float* W2  = (const float*)d_in[5];
    const float* b2  = (const float*)d_in[6];
    const float* W3  = (const float*)d_in[7];
    const float* b3  = (const float*)d_in[8];
    float* out = (float*)d_out;

    const int N = in_sizes[0] / HID;   // 100000
    const int E = in_sizes[1];         // 500000

    // int8 layout: AB8 | scales | wtab | bias256
    const size_t ab8_bytes  = (size_t)N * 256;                       // 25.6 MB
    const size_t sc_off     = (ab8_bytes + 255) & ~(size_t)255;
    const size_t sc_bytes   = (size_t)N * sizeof(float2);            // 800 KB
    const size_t wt_off     = (sc_off + sc_bytes + 255) & ~(size_t)255;
    const size_t wt_bytes   = (size_t)64 * 64 * 8 * sizeof(unsigned short);
    const size_t bi_off     = wt_off + wt_bytes;
    const size_t need_i8    = bi_off + 256 * sizeof(float);

    const size_t ab16_bytes = (size_t)N * 256 * sizeof(unsigned short);

    if (need_i8 <= ws_size) {
        signed char*    AB8     = (signed char*)d_ws;
        float2*         scales  = (float2*)((char*)d_ws + sc_off);
        unsigned short* wtab    = (unsigned short*)((char*)d_ws + wt_off);
        float*          bias256 = (float*)((char*)d_ws + bi_off);
        prep_kernel<<<16, 256, 0, stream>>>(W1, b1, wtab, bias256);
        node_stage_i8_kernel<<<(N + 63) / 64, 256, 0, stream>>>(
            h, wtab, bias256, AB8, scales, N);
        edge_stage_i8_kernel<<<(E + 63) / 64, 256, 0, stream>>>(
            AB8, scales, src, dst, W2, b2, W3, b3, out, E);
    } else if (ab16_bytes <= ws_size) {
        unsigned short* AB = (unsigned short*)d_ws;
        node_stage_kernel<<<1563, 256, 0, stream>>>(h, W1, b1, AB, N);
        edge_stage_kernel<<<(E + 63) / 64, 256, 0, stream>>>(AB, src, dst, W2, b2, W3, b3, out, E);
    } else {
        edge_direct_kernel<<<E, 256, 0, stream>>>(h, src, dst, W1, b1, W2, b2, W3, b3, out, E);
    }
}